// Round 3
// baseline (916.415 us; speedup 1.0000x reference)
//
#include <hip/hip_runtime.h>
#include <cstdint>
#include <cstddef>

// Problem constants (fixed shapes from setup_inputs)
#define Tt 4096      // tokens = B*S
#define Hd 2048      // hidden
#define Fd 2048      // ffn
#define En 8         // experts
#define Rcap 9216    // 8192 assignments + 8*128 padding

typedef short bf16x8 __attribute__((ext_vector_type(8)));
typedef float f32x4 __attribute__((ext_vector_type(4)));
typedef unsigned int u32;
typedef u32 __attribute__((address_space(1))) gas_u32;
typedef u32 __attribute__((address_space(3))) las_u32;

__device__ __forceinline__ unsigned short f2bf(float f) {
    u32 u = __builtin_bit_cast(u32, f);
    u = (u + 0x7FFFu + ((u >> 16) & 1u)) >> 16;   // round-to-nearest-even
    return (unsigned short)u;
}
__device__ __forceinline__ float bf2f(unsigned short s) {
    return __builtin_bit_cast(float, ((u32)s) << 16);
}

// ------------- Router: fp32 logits, softmax, top-2, renorm; + assignment ----
__global__ __launch_bounds__(256) void router_kernel(
    const float* __restrict__ x, const float* __restrict__ gate,
    int* __restrict__ topi, float* __restrict__ topw,
    int* __restrict__ cnt, int* __restrict__ posbuf)
{
    const int t = blockIdx.x;
    const float* xr = x + (size_t)t * Hd;
    float acc[En];
    #pragma unroll
    for (int e = 0; e < En; ++e) acc[e] = 0.f;
    for (int h = threadIdx.x; h < Hd; h += 256) {
        const float xv = xr[h];
        #pragma unroll
        for (int e = 0; e < En; ++e) acc[e] += xv * gate[e * Hd + h];
    }
    #pragma unroll
    for (int e = 0; e < En; ++e) {
        float v = acc[e];
        for (int d = 32; d > 0; d >>= 1) v += __shfl_down(v, d, 64);
        acc[e] = v;
    }
    __shared__ float red[En][4];
    const int lane = threadIdx.x & 63, wv = threadIdx.x >> 6;
    if (lane == 0) {
        #pragma unroll
        for (int e = 0; e < En; ++e) red[e][wv] = acc[e];
    }
    __syncthreads();
    if (threadIdx.x == 0) {
        float l[En];
        #pragma unroll
        for (int e = 0; e < En; ++e) l[e] = red[e][0] + red[e][1] + red[e][2] + red[e][3];
        float m = l[0];
        #pragma unroll
        for (int e = 1; e < En; ++e) m = fmaxf(m, l[e]);
        float p[En];
        #pragma unroll
        for (int e = 0; e < En; ++e) p[e] = expf(l[e] - m);
        int i1 = 0;
        #pragma unroll
        for (int e = 1; e < En; ++e) if (p[e] > p[i1]) i1 = e;
        int i2 = (i1 == 0) ? 1 : 0;
        #pragma unroll
        for (int e = 0; e < En; ++e) if (e != i1 && p[e] > p[i2]) i2 = e;
        const float s = p[i1] + p[i2];
        topi[2 * t] = i1; topi[2 * t + 1] = i2;
        topw[2 * t] = p[i1] / s; topw[2 * t + 1] = p[i2] / s;
        posbuf[2 * t]     = atomicAdd(&cnt[i1], 1);
        posbuf[2 * t + 1] = atomicAdd(&cnt[i2], 1);
    }
}

__global__ void scan_kernel(const int* __restrict__ cnt, int* __restrict__ off,
                            int* __restrict__ pcnt)
{
    if (threadIdx.x == 0 && blockIdx.x == 0) {
        int a = 0;
        for (int e = 0; e < En; ++e) {
            off[e] = a;
            const int pc = (cnt[e] + 127) & ~127;
            pcnt[e] = pc;
            a += pc;
        }
    }
}

// Gather x rows -> bf16 Xg (permuted by expert); record row/weight.
__global__ __launch_bounds__(256) void gather_kernel(
    const float* __restrict__ x, const int* __restrict__ topi,
    const float* __restrict__ topw, const int* __restrict__ off,
    const int* __restrict__ posbuf, unsigned short* __restrict__ Xg,
    int* __restrict__ rowof, float* __restrict__ wrow)
{
    const int entry = blockIdx.x;           // 0..8191
    const int t = entry >> 1;
    const int e = topi[entry];
    const int row = off[e] + posbuf[entry];
    if (threadIdx.x == 0) { rowof[entry] = row; wrow[row] = topw[entry]; }
    const float4* src = (const float4*)(x + (size_t)t * Hd);
    const int i = threadIdx.x;              // 8 elems per thread
    const float4 a = src[2 * i], b = src[2 * i + 1];
    unsigned short o[8];
    o[0] = f2bf(a.x); o[1] = f2bf(a.y); o[2] = f2bf(a.z); o[3] = f2bf(a.w);
    o[4] = f2bf(b.x); o[5] = f2bf(b.y); o[6] = f2bf(b.z); o[7] = f2bf(b.w);
    ((uint4*)(Xg + (size_t)row * Hd))[i] = *(const uint4*)o;
}

// ------- Weight transpose + bf16: [E][K][N] -> [E][N][K], 64x64 tiles -------
__global__ __launch_bounds__(256) void transpose_kernel(
    const float* __restrict__ w1s, const float* __restrict__ w3s,
    const float* __restrict__ w2s, unsigned short* __restrict__ w1T,
    unsigned short* __restrict__ w3T, unsigned short* __restrict__ w2T)
{
    __shared__ float tile[64][65];
    const int z = blockIdx.z, tensor = z >> 3, e = z & 7;
    const float* src = (tensor == 0) ? w1s : (tensor == 1) ? w3s : w2s;
    unsigned short* dst = (tensor == 0) ? w1T : (tensor == 1) ? w3T : w2T;
    const int c0 = blockIdx.x * 64, r0 = blockIdx.y * 64;
    const size_t base = (size_t)e * 2048 * 2048;
    const int tid = threadIdx.x;
    const int ltx = tid & 15, lty = tid >> 4;          // load: 16x16 float4
    #pragma unroll
    for (int p = 0; p < 4; ++p) {
        const int rr = lty + p * 16;
        const float4 v = *(const float4*)(src + base + (size_t)(r0 + rr) * 2048 + c0 + ltx * 4);
        tile[rr][ltx * 4 + 0] = v.x;
        tile[rr][ltx * 4 + 1] = v.y;
        tile[rr][ltx * 4 + 2] = v.z;
        tile[rr][ltx * 4 + 3] = v.w;
    }
    __syncthreads();
    const int rx = tid & 7, cy = tid >> 3;             // store: 8 bf16 along r
    #pragma unroll
    for (int p = 0; p < 2; ++p) {
        const int cc = cy + p * 32;
        unsigned short o[8];
        #pragma unroll
        for (int j = 0; j < 8; ++j) o[j] = f2bf(tile[rx * 8 + j][cc]);
        *(uint4*)(dst + base + (size_t)(c0 + cc) * 2048 + r0 + rx * 8) = *(const uint4*)o;
    }
}

// ------- Fused GEMM1: G = silu(Xg*W1^T) * (Xg*W3^T), bf16, 128x64 tiles -----
// Wave split: wv&1 = M-half, wv>>1 = tensor (0:w1, 1:w3). h3 waves pass their
// tile to h1 waves through LDS in the epilogue; only G hits HBM.
// NOTE: each global_load_lds(16) writes 64 lanes x 16B = 512 shorts — group
// destination stride MUST be 512 shorts (round-2 bug: 1024 stomped LDS).
__global__ __launch_bounds__(256) void gemm13_kernel(
    const unsigned short* __restrict__ Xg,
    const unsigned short* __restrict__ w1T,
    const unsigned short* __restrict__ w3T,
    unsigned short* __restrict__ G,
    const int* __restrict__ off, const int* __restrict__ pcnt)
{
    const int e = blockIdx.z;
    const int mt = blockIdx.y;
    const int pc = pcnt[e];
    if (mt * 128 >= pc) return;
    const int nt = blockIdx.x;                  // 32 tiles of 64 cols
    const int row0 = off[e] + mt * 128;

    const unsigned short* A  = Xg + (size_t)row0 * 2048;
    const unsigned short* B1 = w1T + (size_t)e * 2048 * 2048 + (size_t)nt * 64 * 2048;
    const unsigned short* B3 = w3T + (size_t)e * 2048 * 2048 + (size_t)nt * 64 * 2048;

    __shared__ __align__(16) unsigned short As[128 * 64];   // 16 KiB
    __shared__ __align__(16) unsigned short Bs1[64 * 64];   // 8 KiB
    __shared__ __align__(16) unsigned short Bs3[64 * 64];   // 8 KiB

    const int tid = threadIdx.x;
    const int lane = tid & 63;
    const int wv = tid >> 6;
    const int wm = wv & 1, wt = wv >> 1;
    const int quad = lane >> 4, l16 = lane & 15;
    const unsigned short* BsW = (wt == 0) ? Bs1 : Bs3;

    f32x4 acc[4][4];
    const f32x4 zero4 = {0.f, 0.f, 0.f, 0.f};
    #pragma unroll
    for (int i = 0; i < 4; ++i)
        #pragma unroll
        for (int j = 0; j < 4; ++j) acc[i][j] = zero4;

    for (int kt = 0; kt < 2048; kt += 64) {
        __syncthreads();
        #pragma unroll
        for (int i = 0; i < 4; ++i) {           // A: 1024 chunk-slots
            const int grp = i * 4 + wv;
            const int idx = grp * 64 + lane;
            const int r = idx >> 3;
            const int kc = (idx & 7) ^ (r & 7);
            __builtin_amdgcn_global_load_lds(
                (const gas_u32*)(A + (size_t)r * 2048 + kt + kc * 8),
                (las_u32*)(As + (size_t)grp * 512), 16, 0, 0);
        }
        #pragma unroll
        for (int i = 0; i < 2; ++i) {           // B1/B3: 512 chunk-slots each
            const int grp = i * 4 + wv;
            const int idx = grp * 64 + lane;
            const int r = idx >> 3;
            const int kc = (idx & 7) ^ (r & 7);
            __builtin_amdgcn_global_load_lds(
                (const gas_u32*)(B1 + (size_t)r * 2048 + kt + kc * 8),
                (las_u32*)(Bs1 + (size_t)grp * 512), 16, 0, 0);
            __builtin_amdgcn_global_load_lds(
                (const gas_u32*)(B3 + (size_t)r * 2048 + kt + kc * 8),
                (las_u32*)(Bs3 + (size_t)grp * 512), 16, 0, 0);
        }
        __syncthreads();
        #pragma unroll
        for (int ks = 0; ks < 2; ++ks) {
            const int ck = ks * 4 + quad;
            bf16x8 af[4], bfr[4];
            #pragma unroll
            for (int mi = 0; mi < 4; ++mi) {
                const int m = wm * 64 + mi * 16 + l16;
                af[mi] = *(const bf16x8*)(As + (m * 8 + (ck ^ (m & 7))) * 8);
            }
            #pragma unroll
            for (int ni = 0; ni < 4; ++ni) {
                const int n = ni * 16 + l16;
                bfr[ni] = *(const bf16x8*)(BsW + (n * 8 + (ck ^ (n & 7))) * 8);
            }
            #pragma unroll
            for (int mi = 0; mi < 4; ++mi)
                #pragma unroll
                for (int ni = 0; ni < 4; ++ni)
                    acc[mi][ni] = __builtin_amdgcn_mfma_f32_16x16x32_bf16(
                        af[mi], bfr[ni], acc[mi][ni], 0, 0, 0);
        }
    }

    // Epilogue: h3 waves -> LDS; h1 waves read, silu*mul, store G.
    __syncthreads();
    unsigned short* Gx = As;                    // 128x64 bf16 = 16 KiB
    if (wt == 1) {
        #pragma unroll
        for (int mi = 0; mi < 4; ++mi) {
            const int rb = wm * 64 + mi * 16 + quad * 4;
            #pragma unroll
            for (int ni = 0; ni < 4; ++ni) {
                const int col = ni * 16 + l16;
                #pragma unroll
                for (int r = 0; r < 4; ++r)
                    Gx[(rb + r) * 64 + col] = f2bf(acc[mi][ni][r]);
            }
        }
    }
    __syncthreads();
    if (wt == 0) {
        #pragma unroll
        for (int mi = 0; mi < 4; ++mi) {
            const int rb = wm * 64 + mi * 16 + quad * 4;
            #pragma unroll
            for (int ni = 0; ni < 4; ++ni) {
                const int col = ni * 16 + l16;
                const int gcol = nt * 64 + col;
                #pragma unroll
                for (int r = 0; r < 4; ++r) {
                    const float h1 = acc[mi][ni][r];
                    const float h3 = bf2f(Gx[(rb + r) * 64 + col]);
                    const float s = h1 / (1.f + expf(-h1));
                    G[(size_t)(row0 + rb + r) * 2048 + gcol] = f2bf(s * h3);
                }
            }
        }
    }
}

// ------- GEMM2: OR[r] = wrow[r] * (G[r] * W2^T), bf16 out, plain stores -----
__global__ __launch_bounds__(256) void gemm2_kernel(
    const unsigned short* __restrict__ G,
    const unsigned short* __restrict__ w2T,
    unsigned short* __restrict__ OR,
    const int* __restrict__ off, const int* __restrict__ pcnt,
    const float* __restrict__ wrow)
{
    const int e = blockIdx.z;
    const int mt = blockIdx.y;
    const int pc = pcnt[e];
    if (mt * 128 >= pc) return;
    const int nt = blockIdx.x;
    const int row0 = off[e] + mt * 128;

    const unsigned short* A = G + (size_t)row0 * 2048;
    const unsigned short* B = w2T + (size_t)e * 2048 * 2048 + (size_t)nt * 128 * 2048;

    __shared__ __align__(16) unsigned short As[128 * 64];
    __shared__ __align__(16) unsigned short Bs[128 * 64];

    const int tid = threadIdx.x;
    const int lane = tid & 63;
    const int wv = tid >> 6;
    const int wm = wv & 1, wn = wv >> 1;
    const int quad = lane >> 4, l16 = lane & 15;

    f32x4 acc[4][4];
    const f32x4 zero4 = {0.f, 0.f, 0.f, 0.f};
    #pragma unroll
    for (int i = 0; i < 4; ++i)
        #pragma unroll
        for (int j = 0; j < 4; ++j) acc[i][j] = zero4;

    for (int kt = 0; kt < 2048; kt += 64) {
        __syncthreads();
        #pragma unroll
        for (int i = 0; i < 4; ++i) {
            const int grp = i * 4 + wv;
            const int idx = grp * 64 + lane;
            const int r = idx >> 3;
            const int kc = (idx & 7) ^ (r & 7);
            __builtin_amdgcn_global_load_lds(
                (const gas_u32*)(A + (size_t)r * 2048 + kt + kc * 8),
                (las_u32*)(As + (size_t)grp * 512), 16, 0, 0);
            __builtin_amdgcn_global_load_lds(
                (const gas_u32*)(B + (size_t)r * 2048 + kt + kc * 8),
                (las_u32*)(Bs + (size_t)grp * 512), 16, 0, 0);
        }
        __syncthreads();
        #pragma unroll
        for (int ks = 0; ks < 2; ++ks) {
            const int ck = ks * 4 + quad;
            bf16x8 af[4], bfr[4];
            #pragma unroll
            for (int mi = 0; mi < 4; ++mi) {
                const int m = wm * 64 + mi * 16 + l16;
                af[mi] = *(const bf16x8*)(As + (m * 8 + (ck ^ (m & 7))) * 8);
            }
            #pragma unroll
            for (int ni = 0; ni < 4; ++ni) {
                const int n = wn * 64 + ni * 16 + l16;
                bfr[ni] = *(const bf16x8*)(Bs + (n * 8 + (ck ^ (n & 7))) * 8);
            }
            #pragma unroll
            for (int mi = 0; mi < 4; ++mi)
                #pragma unroll
                for (int ni = 0; ni < 4; ++ni)
                    acc[mi][ni] = __builtin_amdgcn_mfma_f32_16x16x32_bf16(
                        af[mi], bfr[ni], acc[mi][ni], 0, 0, 0);
        }
    }

    #pragma unroll
    for (int mi = 0; mi < 4; ++mi) {
        const int rbase = row0 + wm * 64 + mi * 16 + quad * 4;
        #pragma unroll
        for (int r = 0; r < 4; ++r) {
            const int rg = rbase + r;
            const float w = wrow[rg];           // 0.0 on pad rows
            #pragma unroll
            for (int ni = 0; ni < 4; ++ni) {
                const int col = nt * 128 + wn * 64 + ni * 16 + l16;
                OR[(size_t)rg * 2048 + col] = f2bf(acc[mi][ni][r] * w);
            }
        }
    }
}

// ------- Combine: out[t] = OR[row(t,0)] + OR[row(t,1)]  (fp32 out) ----------
__global__ __launch_bounds__(256) void combine_kernel(
    const unsigned short* __restrict__ OR, const int* __restrict__ rowof,
    float* __restrict__ out)
{
    const int t = blockIdx.x;
    const int r0 = rowof[2 * t], r1 = rowof[2 * t + 1];
    const int j = threadIdx.x;
    const uint4 a = *(const uint4*)(OR + (size_t)r0 * 2048 + j * 8);
    const uint4 b = *(const uint4*)(OR + (size_t)r1 * 2048 + j * 8);
    const unsigned short* pa = (const unsigned short*)&a;
    const unsigned short* pb = (const unsigned short*)&b;
    float o[8];
    #pragma unroll
    for (int k = 0; k < 8; ++k) o[k] = bf2f(pa[k]) + bf2f(pb[k]);
    float* dst = out + (size_t)t * 2048 + j * 8;
    *(float4*)dst = *(const float4*)o;
    *(float4*)(dst + 4) = *(const float4*)(o + 4);
}

// ---------------- Workspace layout ------------------------------------------
static constexpr size_t SZ_WT  = (size_t)En * 2048 * 2048 * 2;  // 64 MiB each
static constexpr size_t SZ_RB  = (size_t)Rcap * 2048 * 2;       // 36 MiB each
static constexpr size_t O_W1T  = 0;
static constexpr size_t O_W3T  = O_W1T + SZ_WT;
static constexpr size_t O_W2T  = O_W3T + SZ_WT;
static constexpr size_t O_XG   = O_W2T + SZ_WT;
static constexpr size_t O_G    = O_XG + SZ_RB;
static constexpr size_t O_OR   = O_G + SZ_RB;
static constexpr size_t O_TOPI = O_OR + SZ_RB;
static constexpr size_t O_TOPW = O_TOPI + (size_t)Tt * 2 * 4;
static constexpr size_t O_POS  = O_TOPW + (size_t)Tt * 2 * 4;
static constexpr size_t O_ROW  = O_POS + (size_t)Tt * 2 * 4;
static constexpr size_t O_OFF  = O_ROW + (size_t)Tt * 2 * 4;
static constexpr size_t O_PCNT = O_OFF + 64;
static constexpr size_t O_CNT  = O_PCNT + 64;          // ---- zeroed region ----
static constexpr size_t O_WROW = O_CNT + 64;
static constexpr size_t ZERO_SZ = 64 + (size_t)Rcap * 4;

extern "C" void kernel_launch(void* const* d_in, const int* in_sizes, int n_in,
                              void* d_out, int out_size, void* d_ws, size_t ws_size,
                              hipStream_t stream)
{
    const float* x    = (const float*)d_in[0];
    const float* gate = (const float*)d_in[1];
    const float* w1s  = (const float*)d_in[2];
    const float* w2s  = (const float*)d_in[3];
    const float* w3s  = (const float*)d_in[4];
    float* out = (float*)d_out;
    char* ws = (char*)d_ws;

    unsigned short* w1T = (unsigned short*)(ws + O_W1T);
    unsigned short* w3T = (unsigned short*)(ws + O_W3T);
    unsigned short* w2T = (unsigned short*)(ws + O_W2T);
    unsigned short* Xg  = (unsigned short*)(ws + O_XG);
    unsigned short* G   = (unsigned short*)(ws + O_G);
    unsigned short* OR  = (unsigned short*)(ws + O_OR);
    int*   topi   = (int*)(ws + O_TOPI);
    float* topw   = (float*)(ws + O_TOPW);
    int*   posbuf = (int*)(ws + O_POS);
    int*   rowof  = (int*)(ws + O_ROW);
    int*   off    = (int*)(ws + O_OFF);
    int*   pcnt   = (int*)(ws + O_PCNT);
    int*   cnt    = (int*)(ws + O_CNT);
    float* wrow   = (float*)(ws + O_WROW);

    hipMemsetAsync(ws + O_XG, 0, SZ_RB, stream);           // pad rows read as 0
    hipMemsetAsync(ws + O_CNT, 0, ZERO_SZ, stream);        // cnt + wrow

    transpose_kernel<<<dim3(32, 32, 24), 256, 0, stream>>>(w1s, w3s, w2s, w1T, w3T, w2T);
    router_kernel<<<Tt, 256, 0, stream>>>(x, gate, topi, topw, cnt, posbuf);
    scan_kernel<<<1, 64, 0, stream>>>(cnt, off, pcnt);
    gather_kernel<<<Tt * 2, 256, 0, stream>>>(x, topi, topw, off, posbuf, Xg, rowof, wrow);

    // G = silu(Xg*W1^T) * (Xg*W3^T), fused
    gemm13_kernel<<<dim3(32, 32, 8), 256, 0, stream>>>(Xg, w1T, w3T, G, off, pcnt);
    // OR[r] = wrow[r] * (G[r] * W2^T)
    gemm2_kernel<<<dim3(16, 32, 8), 256, 0, stream>>>(G, w2T, OR, off, pcnt, wrow);
    // out[t] = OR[r0] + OR[r1]
    combine_kernel<<<Tt, 256, 0, stream>>>(OR, rowof, out);
}